// Round 1
// baseline (127.270 us; speedup 1.0000x reference)
//
#include <hip/hip_runtime.h>

// LSH attention (Reformer-style) on MI355X.
// Key reduction: out == v exactly (mask only admits same-position matches;
// softmax over identical values; cross-round weights sum to 1).
// Only real compute: buckets = argmax over [r, -r] of r = qk @ rotations.

namespace {
constexpr int S_LEN   = 8192;
constexpr int D_DIM   = 64;
constexpr int N_HASH  = 8;
constexpr int N_BUCK  = 128;   // n_buckets
constexpr int HALF_I  = 64;    // n_buckets / 2
constexpr int T_TILE  = 128;   // t positions per block
constexpr int THREADS = 256;
constexpr int BATCH   = 4;
constexpr long long OUT0_ELEMS = (long long)BATCH * S_LEN * D_DIM; // 2,097,152
}

struct Red {
  double vp;  // max over +r in this thread's i-slice
  double vn;  // max over -r
  int ip;     // argmax i for +r (global i, first occurrence)
  int in_;    // argmax i for -r
};

__global__ __launch_bounds__(THREADS) void lsh_bucket_kernel(
    const float* __restrict__ qk, const float* __restrict__ rot,
    float* __restrict__ outb) {
  const int b    = blockIdx.z;
  const int h    = blockIdx.y;
  const int tile = blockIdx.x;
  const int tid  = threadIdx.x;
  const int ii   = tid & 7;   // 8 i-groups, 8 i each
  const int ti   = tid >> 3;  // 32 t-groups, 4 t each -> 128 t

  __shared__ float lrot[D_DIM * HALF_I];  // [f][i], 16 KB
  __shared__ Red   red[T_TILE][8];        // 24 KB

  // Stage rotations slice for this h: rot[f, h, i], global stride 512 per f.
  for (int k = tid; k < D_DIM * HALF_I; k += THREADS) {
    const int f = k >> 6;
    const int i = k & 63;
    lrot[k] = rot[f * (N_HASH * HALF_I) + h * HALF_I + i];
  }
  __syncthreads();

  const int tbase = tile * T_TILE + ti * 4;
  const float* qp = qk + ((size_t)b * S_LEN + tbase) * D_DIM;

  double acc[4][8];
#pragma unroll
  for (int j = 0; j < 4; ++j)
#pragma unroll
    for (int k = 0; k < 8; ++k) acc[j][k] = 0.0;

  for (int f0 = 0; f0 < D_DIM; f0 += 4) {
    // 4 q rows, 4 f's each, vectorized global loads (hit L1/L2).
    float qbuf[4][4];
#pragma unroll
    for (int j = 0; j < 4; ++j)
      *(float4*)qbuf[j] = *(const float4*)(qp + j * D_DIM + f0);

#pragma unroll
    for (int fo = 0; fo < 4; ++fo) {
      const float* lr = &lrot[(f0 + fo) * HALF_I + ii * 8];
      float4 ra = *(const float4*)(lr);
      float4 rb = *(const float4*)(lr + 4);
      double rd[8] = {(double)ra.x, (double)ra.y, (double)ra.z, (double)ra.w,
                      (double)rb.x, (double)rb.y, (double)rb.z, (double)rb.w};
      double qd[4];
#pragma unroll
      for (int j = 0; j < 4; ++j) qd[j] = (double)qbuf[j][fo];
#pragma unroll
      for (int j = 0; j < 4; ++j)
#pragma unroll
        for (int k = 0; k < 8; ++k)
          acc[j][k] += qd[j] * rd[k];
    }
  }

  // Per-thread argmax over this thread's 8-i slice, for each of 4 t's.
#pragma unroll
  for (int j = 0; j < 4; ++j) {
    double vp = -1e300, vn = -1e300;
    int ip = 0, in_ = 0;
#pragma unroll
    for (int k = 0; k < 8; ++k) {
      const double v = acc[j][k];
      const int gi = ii * 8 + k;
      if (v > vp)  { vp = v;  ip = gi; }   // strict > keeps first occurrence
      if (-v > vn) { vn = -v; in_ = gi; }
    }
    Red r; r.vp = vp; r.vn = vn; r.ip = ip; r.in_ = in_;
    red[ti * 4 + j][ii] = r;
  }
  __syncthreads();

  // One thread per t: combine 8 slices in ascending-i order.
  if (tid < T_TILE) {
    double Vp = -1e300, Vn = -1e300;
    int Ip = 0, In = 0;
#pragma unroll
    for (int e = 0; e < 8; ++e) {
      const Red r = red[tid][e];
      if (r.vp > Vp) { Vp = r.vp; Ip = r.ip; }
      if (r.vn > Vn) { Vn = r.vn; In = r.in_; }
    }
    // Concatenated array is [r, -r]: on exact tie, first half wins.
    const int bucket = (Vp >= Vn) ? Ip : (HALF_I + In);
    outb[((size_t)b * N_HASH + h) * S_LEN + tile * T_TILE + tid] =
        (float)(bucket + h * N_BUCK);
  }
}

extern "C" void kernel_launch(void* const* d_in, const int* in_sizes, int n_in,
                              void* d_out, int out_size, void* d_ws, size_t ws_size,
                              hipStream_t stream) {
  const float* qk  = (const float*)d_in[0];
  const float* v   = (const float*)d_in[1];
  const float* rot = (const float*)d_in[2];
  float* out = (float*)d_out;

  // Output 0: out == v (see analysis). Straight d2d copy.
  hipMemcpyAsync(out, v, (size_t)OUT0_ELEMS * sizeof(float),
                 hipMemcpyDeviceToDevice, stream);

  // Output 1: buckets, written as float values.
  dim3 grid(S_LEN / T_TILE, N_HASH, BATCH);
  lsh_bucket_kernel<<<grid, THREADS, 0, stream>>>(qk, rot, out + OUT0_ELEMS);
}

// Round 2
// 117.393 us; speedup vs baseline: 1.0841x; 1.0841x over previous
//
#include <hip/hip_runtime.h>

// LSH attention (Reformer-style) on MI355X.
// out0 == v exactly (mask admits exactly one same-position match per row;
// softmax one-hot; cross-round weights sum to 1)  -> fused d2d copy.
// out1 = buckets: fp32 GEMM + certified top-2 argmax; rows with
// top1-top2 < MARGIN repaired in fp64 (bitwise-identical to the passing
// round-1 fp64 kernel's sequential-f accumulation).

namespace {
constexpr int S_LEN   = 8192;
constexpr int D_DIM   = 64;
constexpr int N_HASH  = 8;
constexpr int N_BUCK  = 128;
constexpr int HALF_I  = 64;    // n_buckets / 2
constexpr int T_TILE  = 256;   // t rows per block
constexpr int THREADS = 256;
constexpr int BATCH   = 4;
constexpr float MARGIN = 4e-3f;  // >> 2x max fp32 accum error (~1e-4)
constexpr long long OUT0_ELEMS = (long long)BATCH * S_LEN * D_DIM;
}

__global__ __launch_bounds__(THREADS) void lsh_fused_kernel(
    const float* __restrict__ qk, const float* __restrict__ v,
    const float* __restrict__ rot, float* __restrict__ out) {
  const int b    = blockIdx.z;
  const int h    = blockIdx.y;
  const int tile = blockIdx.x;
  const int tid  = threadIdx.x;
  const int ii   = tid & 7;   // 8 i-groups x 8 i
  const int ti   = tid >> 3;  // 32 t-groups x 8 t

  __shared__ float lrot[D_DIM * HALF_I];  // [f][i], 16 KB
  __shared__ int s_cnt;
  __shared__ int s_list[T_TILE];

  if (tid == 0) s_cnt = 0;

  // ---- fused out0 = v copy (1024 blocks x 512 float4) ----
  {
    const int bid = blockIdx.x + gridDim.x * (blockIdx.y + gridDim.y * blockIdx.z);
    const float4* vs = (const float4*)v;
    float4* vd = (float4*)out;
    const int base = bid * 512 + tid;
    vd[base]       = vs[base];
    vd[base + 256] = vs[base + 256];
  }

  // ---- stage rotations[f, h, :] into LDS (f-major, 64 floats per f) ----
  {
    const float4* r4 = (const float4*)rot;
    float4* l4 = (float4*)lrot;
    for (int k = tid; k < D_DIM * (HALF_I / 4); k += THREADS) {
      const int f  = k >> 4;
      const int i4 = k & 15;
      l4[f * 16 + i4] = r4[f * (N_HASH * HALF_I / 4) + h * 16 + i4];
    }
  }
  __syncthreads();

  const int trow0 = tile * T_TILE + ti * 8;
  const float* qp = qk + ((size_t)b * S_LEN + trow0) * D_DIM;

  float acc[8][8];
#pragma unroll
  for (int j = 0; j < 8; ++j)
#pragma unroll
    for (int k = 0; k < 8; ++k) acc[j][k] = 0.0f;

  for (int f0 = 0; f0 < D_DIM; f0 += 4) {
    float qv[8][4];
#pragma unroll
    for (int j = 0; j < 8; ++j)
      *(float4*)qv[j] = *(const float4*)(qp + j * D_DIM + f0);

#pragma unroll
    for (int fo = 0; fo < 4; ++fo) {
      const float* lr = &lrot[(f0 + fo) * HALF_I + ii * 8];
      const float4 ra = *(const float4*)(lr);
      const float4 rb = *(const float4*)(lr + 4);
      const float r[8] = {ra.x, ra.y, ra.z, ra.w, rb.x, rb.y, rb.z, rb.w};
#pragma unroll
      for (int j = 0; j < 8; ++j)
#pragma unroll
        for (int k = 0; k < 8; ++k)
          acc[j][k] = fmaf(qv[j][fo], r[k], acc[j][k]);
    }
  }

  const int h_off = h * N_BUCK;
  float* outb = out + OUT0_ELEMS + ((size_t)b * N_HASH + h) * S_LEN + tile * T_TILE;

  // ---- per-row certified argmax: top-2 over the 128 candidates [r, -r] ----
#pragma unroll
  for (int j = 0; j < 8; ++j) {
    float v1p = -3e38f, v2p = -3e38f; int i1p = 0;
    float v1n = -3e38f, v2n = -3e38f; int i1n = 0;
#pragma unroll
    for (int k = 0; k < 8; ++k) {
      const float val = acc[j][k];
      const int gi = ii * 8 + k;
      if (val > v1p)      { v2p = v1p; v1p = val; i1p = gi; }
      else if (val > v2p) { v2p = val; }
      const float nv = -val;
      if (nv > v1n)       { v2n = v1n; v1n = nv; i1n = gi; }
      else if (nv > v2n)  { v2n = nv; }
    }
    // butterfly across the 8 contiguous ii-lanes of this t-row
#pragma unroll
    for (int m = 1; m < 8; m <<= 1) {
      const float ov1p = __shfl_xor(v1p, m);
      const int   oi1p = __shfl_xor(i1p, m);
      const float ov2p = __shfl_xor(v2p, m);
      if (ov1p > v1p || (ov1p == v1p && oi1p < i1p)) {
        v2p = fmaxf(v1p, ov2p); v1p = ov1p; i1p = oi1p;
      } else {
        v2p = fmaxf(v2p, ov1p);
      }
      const float ov1n = __shfl_xor(v1n, m);
      const int   oi1n = __shfl_xor(i1n, m);
      const float ov2n = __shfl_xor(v2n, m);
      if (ov1n > v1n || (ov1n == v1n && oi1n < i1n)) {
        v2n = fmaxf(v1n, ov2n); v1n = ov1n; i1n = oi1n;
      } else {
        v2n = fmaxf(v2n, ov1n);
      }
    }
    if (ii == 0) {
      const int t_local = ti * 8 + j;
      float top1, top2; int bucket;
      if (v1p >= v1n) { top1 = v1p; top2 = fmaxf(v1n, v2p); bucket = i1p; }
      else            { top1 = v1n; top2 = fmaxf(v1p, v2n); bucket = HALF_I + i1n; }
      if (top1 - top2 < MARGIN) {
        s_list[atomicAdd(&s_cnt, 1)] = t_local;   // rare: certify in fp64
      } else {
        outb[t_local] = (float)(bucket + h_off);
      }
    }
  }

  __syncthreads();

  // ---- rare fp64 repair: one wave per flagged row, lane = column i ----
  const int wave = tid >> 6;
  const int lane = tid & 63;
  const int cnt = s_cnt;
  for (int it = wave; it < cnt; it += THREADS / 64) {
    const int tl = s_list[it];
    const float* qrow = qk + ((size_t)b * S_LEN + tile * T_TILE + tl) * D_DIM;
    double dot = 0.0;
#pragma unroll 8
    for (int f = 0; f < D_DIM; ++f)
      dot = fma((double)qrow[f], (double)lrot[f * HALF_I + lane], dot);
    double vp = dot, vn = -dot;
    int ip = lane, in_ = HALF_I + lane;
#pragma unroll
    for (int m = 1; m < 64; m <<= 1) {
      const double ovp = __shfl_xor(vp, m);
      const int   oip = __shfl_xor(ip, m);
      if (ovp > vp || (ovp == vp && oip < ip)) { vp = ovp; ip = oip; }
      const double ovn = __shfl_xor(vn, m);
      const int   oin = __shfl_xor(in_, m);
      if (ovn > vn || (ovn == vn && oin < in_)) { vn = ovn; in_ = oin; }
    }
    if (lane == 0) {
      const int bucket = (vp >= vn) ? ip : in_;
      outb[tl] = (float)(bucket + h_off);
    }
  }
}

extern "C" void kernel_launch(void* const* d_in, const int* in_sizes, int n_in,
                              void* d_out, int out_size, void* d_ws, size_t ws_size,
                              hipStream_t stream) {
  const float* qk  = (const float*)d_in[0];
  const float* v   = (const float*)d_in[1];
  const float* rot = (const float*)d_in[2];
  float* out = (float*)d_out;

  dim3 grid(S_LEN / T_TILE, N_HASH, BATCH);
  lsh_fused_kernel<<<grid, THREADS, 0, stream>>>(qk, v, rot, out);
}

// Round 3
// 107.979 us; speedup vs baseline: 1.1787x; 1.0872x over previous
//
#include <hip/hip_runtime.h>

// LSH attention (Reformer-style) on MI355X.
// out0 == v exactly (mask admits exactly one same-position match per row;
// softmax one-hot; cross-round weights sum to 1)  -> fused d2d copy.
// out1 = buckets: fp32 GEMM + certified top-2 argmax; rows with
// top1-top2 < MARGIN repaired in fp64 (bitwise-identical to the passing
// round-1 fp64 kernel's sequential-f accumulation).
// R3: T_TILE 128 (grid 2048) for occupancy+tail, double-buffered q prefetch.

namespace {
constexpr int S_LEN   = 8192;
constexpr int D_DIM   = 64;
constexpr int N_HASH  = 8;
constexpr int N_BUCK  = 128;
constexpr int HALF_I  = 64;    // n_buckets / 2
constexpr int T_TILE  = 128;   // t rows per block
constexpr int THREADS = 256;
constexpr int BATCH   = 4;
constexpr float MARGIN = 4e-3f;  // >> 2x max fp32 accum error (~1e-4)
constexpr long long OUT0_ELEMS = (long long)BATCH * S_LEN * D_DIM;
}

__global__ __launch_bounds__(THREADS) void lsh_fused_kernel(
    const float* __restrict__ qk, const float* __restrict__ v,
    const float* __restrict__ rot, float* __restrict__ out) {
  const int b    = blockIdx.z;
  const int h    = blockIdx.y;
  const int tile = blockIdx.x;
  const int tid  = threadIdx.x;
  const int ii   = tid & 7;   // 8 i-groups x 8 i
  const int ti   = tid >> 3;  // 32 t-groups x 4 t -> 128 t

  __shared__ float lrot[D_DIM * HALF_I];  // [f][i], 16 KB
  __shared__ int s_cnt;
  __shared__ int s_list[T_TILE];

  if (tid == 0) s_cnt = 0;

  // ---- fused out0 = v copy (2048 blocks x 256 float4) ----
  {
    const int bid = blockIdx.x + gridDim.x * (blockIdx.y + gridDim.y * blockIdx.z);
    ((float4*)out)[bid * THREADS + tid] = ((const float4*)v)[bid * THREADS + tid];
  }

  // ---- stage rotations[f, h, :] into LDS (f-major, 64 floats per f) ----
  {
    const float4* r4 = (const float4*)rot;
    float4* l4 = (float4*)lrot;
#pragma unroll
    for (int it = 0; it < 4; ++it) {
      const int k = it * THREADS + tid;
      const int f  = k >> 4;
      const int i4 = k & 15;
      l4[f * 16 + i4] = r4[f * (N_HASH * HALF_I / 4) + h * 16 + i4];
    }
  }
  __syncthreads();

  const int trow0 = tile * T_TILE + ti * 4;
  const float* qp = qk + ((size_t)b * S_LEN + trow0) * D_DIM;

  float acc[4][8];
#pragma unroll
  for (int j = 0; j < 4; ++j)
#pragma unroll
    for (int k = 0; k < 8; ++k) acc[j][k] = 0.0f;

  float qA[4][4], qB[4][4];
#pragma unroll
  for (int j = 0; j < 4; ++j)
    *(float4*)qA[j] = *(const float4*)(qp + j * D_DIM);

#define LSH_COMPUTE(QBUF, F0)                                            \
  _Pragma("unroll")                                                      \
  for (int fo = 0; fo < 4; ++fo) {                                       \
    const float* lr = &lrot[((F0) + fo) * HALF_I + ii * 8];              \
    const float4 ra = *(const float4*)(lr);                              \
    const float4 rb = *(const float4*)(lr + 4);                          \
    const float r[8] = {ra.x, ra.y, ra.z, ra.w, rb.x, rb.y, rb.z, rb.w}; \
    _Pragma("unroll")                                                    \
    for (int j = 0; j < 4; ++j)                                          \
      _Pragma("unroll")                                                  \
      for (int k = 0; k < 8; ++k)                                        \
        acc[j][k] = fmaf(QBUF[j][fo], r[k], acc[j][k]);                  \
  }

  for (int f0 = 0; f0 < D_DIM; f0 += 8) {
    // prefetch B (f0+4) while computing A (f0)
#pragma unroll
    for (int j = 0; j < 4; ++j)
      *(float4*)qB[j] = *(const float4*)(qp + j * D_DIM + f0 + 4);
    LSH_COMPUTE(qA, f0)
    // prefetch A (f0+8) while computing B (f0+4)
    if (f0 + 8 < D_DIM) {
#pragma unroll
      for (int j = 0; j < 4; ++j)
        *(float4*)qA[j] = *(const float4*)(qp + j * D_DIM + f0 + 8);
    }
    LSH_COMPUTE(qB, f0 + 4)
  }
#undef LSH_COMPUTE

  const int h_off = h * N_BUCK;
  float* outb = out + OUT0_ELEMS + ((size_t)b * N_HASH + h) * S_LEN + tile * T_TILE;

  // ---- per-row certified argmax: top-2 over the 128 candidates [r, -r] ----
#pragma unroll
  for (int j = 0; j < 4; ++j) {
    float v1p = -3e38f, v2p = -3e38f; int i1p = 0;
    float v1n = -3e38f, v2n = -3e38f; int i1n = 0;
#pragma unroll
    for (int k = 0; k < 8; ++k) {
      const float val = acc[j][k];
      const int gi = ii * 8 + k;
      if (val > v1p)      { v2p = v1p; v1p = val; i1p = gi; }
      else if (val > v2p) { v2p = val; }
      const float nv = -val;
      if (nv > v1n)       { v2n = v1n; v1n = nv; i1n = gi; }
      else if (nv > v2n)  { v2n = nv; }
    }
    // butterfly across the 8 contiguous ii-lanes of this t-row
#pragma unroll
    for (int m = 1; m < 8; m <<= 1) {
      const float ov1p = __shfl_xor(v1p, m);
      const int   oi1p = __shfl_xor(i1p, m);
      const float ov2p = __shfl_xor(v2p, m);
      if (ov1p > v1p || (ov1p == v1p && oi1p < i1p)) {
        v2p = fmaxf(v1p, ov2p); v1p = ov1p; i1p = oi1p;
      } else {
        v2p = fmaxf(v2p, ov1p);
      }
      const float ov1n = __shfl_xor(v1n, m);
      const int   oi1n = __shfl_xor(i1n, m);
      const float ov2n = __shfl_xor(v2n, m);
      if (ov1n > v1n || (ov1n == v1n && oi1n < i1n)) {
        v2n = fmaxf(v1n, ov2n); v1n = ov1n; i1n = oi1n;
      } else {
        v2n = fmaxf(v2n, ov1n);
      }
    }
    if (ii == 0) {
      const int t_local = ti * 4 + j;
      float top1, top2; int bucket;
      if (v1p >= v1n) { top1 = v1p; top2 = fmaxf(v1n, v2p); bucket = i1p; }
      else            { top1 = v1n; top2 = fmaxf(v1p, v2n); bucket = HALF_I + i1n; }
      if (top1 - top2 < MARGIN) {
        s_list[atomicAdd(&s_cnt, 1)] = t_local;   // rare: certify in fp64
      } else {
        outb[t_local] = (float)(bucket + h_off);
      }
    }
  }

  __syncthreads();

  // ---- rare fp64 repair: one wave per flagged row, lane = column i ----
  const int wave = tid >> 6;
  const int lane = tid & 63;
  const int cnt = s_cnt;
  for (int it = wave; it < cnt; it += THREADS / 64) {
    const int tl = s_list[it];
    const float* qrow = qk + ((size_t)b * S_LEN + tile * T_TILE + tl) * D_DIM;
    double dot = 0.0;
#pragma unroll 8
    for (int f = 0; f < D_DIM; ++f)
      dot = fma((double)qrow[f], (double)lrot[f * HALF_I + lane], dot);
    double vp = dot, vn = -dot;
    int ip = lane, in_ = HALF_I + lane;
#pragma unroll
    for (int m = 1; m < 64; m <<= 1) {
      const double ovp = __shfl_xor(vp, m);
      const int   oip = __shfl_xor(ip, m);
      if (ovp > vp || (ovp == vp && oip < ip)) { vp = ovp; ip = oip; }
      const double ovn = __shfl_xor(vn, m);
      const int   oin = __shfl_xor(in_, m);
      if (ovn > vn || (ovn == vn && oin < in_)) { vn = ovn; in_ = oin; }
    }
    if (lane == 0) {
      const int bucket = (vp >= vn) ? ip : in_;
      outb[tl] = (float)(bucket + h_off);
    }
  }
}

extern "C" void kernel_launch(void* const* d_in, const int* in_sizes, int n_in,
                              void* d_out, int out_size, void* d_ws, size_t ws_size,
                              hipStream_t stream) {
  const float* qk  = (const float*)d_in[0];
  const float* v   = (const float*)d_in[1];
  const float* rot = (const float*)d_in[2];
  float* out = (float*)d_out;

  dim3 grid(S_LEN / T_TILE, N_HASH, BATCH);
  lsh_fused_kernel<<<grid, THREADS, 0, stream>>>(qk, v, rot, out);
}